// Round 1
// baseline (1854.232 us; speedup 1.0000x reference)
//
#include <hip/hip_runtime.h>
#include <cstddef>

#define NHEADS 8
#define TT 243
#define JJ 17
#define BB 8
#define CC 512
#define HD 64
#define MROWS 33048      // B*T*J
#define TJ 4131          // T*J
#define HJ 136           // H*J

// ---------------------------------------------------------------------------
// Kernel 1: qkv = x @ W_qkv, scattered into q/k/v buffers laid out [B,H,J,T,hd]
// Plain fp32 tiled GEMM: 64x64 tile, BK=16, 256 threads, 4x4 micro-tile.
// ---------------------------------------------------------------------------
__global__ __launch_bounds__(256) void qkv_gemm(
    const float* __restrict__ x, const float* __restrict__ Wqkv,
    float* __restrict__ qb, float* __restrict__ kb, float* __restrict__ vb)
{
    __shared__ float As[16][68];   // [k][m] (transposed on store)
    __shared__ float Bs[16][68];   // [k][n]
    const int tid = threadIdx.x;
    const int tx = tid & 15, ty = tid >> 4;
    const int m0 = blockIdx.y * 64;
    const int n0 = blockIdx.x * 64;
    const int ar = tid >> 2, akc = (tid & 3) << 2;   // A tile: 64 rows x 16 k
    const int br = tid >> 4, bc = (tid & 15) << 2;   // B tile: 16 k x 64 n
    float acc[4][4] = {};

    for (int k0 = 0; k0 < 512; k0 += 16) {
        float4 a4 = make_float4(0.f, 0.f, 0.f, 0.f);
        const int amr = m0 + ar;
        if (amr < MROWS) a4 = *(const float4*)(x + (size_t)amr * 512 + k0 + akc);
        const float4 b4 = *(const float4*)(Wqkv + (size_t)(k0 + br) * 1536 + n0 + bc);
        __syncthreads();
        As[akc + 0][ar] = a4.x; As[akc + 1][ar] = a4.y;
        As[akc + 2][ar] = a4.z; As[akc + 3][ar] = a4.w;
        *(float4*)&Bs[br][bc] = b4;
        __syncthreads();
        #pragma unroll
        for (int k = 0; k < 16; ++k) {
            const float4 av = *(const float4*)&As[k][ty << 2];
            const float4 bv = *(const float4*)&Bs[k][tx << 2];
            const float aa[4] = {av.x, av.y, av.z, av.w};
            const float bb[4] = {bv.x, bv.y, bv.z, bv.w};
            #pragma unroll
            for (int i = 0; i < 4; ++i)
                #pragma unroll
                for (int n = 0; n < 4; ++n)
                    acc[i][n] = fmaf(aa[i], bb[n], acc[i][n]);
        }
    }

    // scatter epilogue: col n -> (which, h, d); row m -> (b, t, j)
    float* dsts[3] = {qb, kb, vb};
    const int nbase = n0 + (tx << 2);          // 4 consecutive cols, same which/h
    const int which = nbase >> 9;
    const int h     = (nbase >> 6) & 7;
    const int d0    = nbase & 63;              // multiple of 4
    float* const dst = dsts[which];
    #pragma unroll
    for (int i = 0; i < 4; ++i) {
        const int m = m0 + (ty << 2) + i;
        if (m < MROWS) {
            const int b = m / TJ;  const int r = m - b * TJ;
            const int t = r / JJ;  const int j = r - t * JJ;
            const size_t base = ((size_t)((b * NHEADS + h) * JJ + j) * TT + t) * HD;
            *(float4*)(dst + base + d0) =
                make_float4(acc[i][0], acc[i][1], acc[i][2], acc[i][3]);
        }
    }
}

// ---------------------------------------------------------------------------
// Kernel 2: fused attention per (b,h,j, 64-row tile).
// Phase1: S^T[s][row] = (q.k)*scale  (GEMM-style, 4x4 micro)
// Phase2: softmax over s per row, blend with att_map, result back into ST
// Phase3: O[row][d] = P @ V
// LDS: ST 256x68 (69.6KB) + Qt 64x68 (17.4KB) + Stg 64x68 (17.4KB) = 104.4KB
// ---------------------------------------------------------------------------
__global__ __launch_bounds__(256) void attn_fused(
    const float* __restrict__ qb, const float* __restrict__ kb,
    const float* __restrict__ vb, const float* __restrict__ att,
    const float* __restrict__ wptr, float* __restrict__ ob)
{
    __shared__ float ST[256][68];   // [s][row]  (scores, then P)
    __shared__ float Qt[64][68];    // [d][row]
    __shared__ float Stg[64][68];   // K chunk [d][ss] / V chunk [sl][d]

    const int tid = threadIdx.x;
    const int tx = tid & 15, ty = tid >> 4;
    const int gid  = blockIdx.x;
    const int tile = gid & 3, bhj = gid >> 2;
    const int row0 = tile << 6;
    const int rows = min(64, TT - row0);

    const float w = wptr[0];
    const float* q  = qb + (size_t)bhj * TT * HD;
    const float* k  = kb + (size_t)bhj * TT * HD;
    const float* v  = vb + (size_t)bhj * TT * HD;
    const float* am = att + (size_t)bhj * TT * TT;

    // Load Q tile transposed: Qt[d][r]
    #pragma unroll
    for (int l = 0; l < 4; ++l) {
        const int idx = tid + (l << 8);
        const int r = idx >> 4;
        const int dc = (idx & 15) << 2;
        float4 v4 = make_float4(0.f, 0.f, 0.f, 0.f);
        if (r < rows) v4 = *(const float4*)(q + (size_t)(row0 + r) * HD + dc);
        Qt[dc + 0][r] = v4.x; Qt[dc + 1][r] = v4.y;
        Qt[dc + 2][r] = v4.z; Qt[dc + 3][r] = v4.w;
    }

    // -------- Phase 1: scores --------
    for (int c = 0; c < 4; ++c) {
        __syncthreads();                       // prev chunk's reads done (and Qt stores)
        #pragma unroll
        for (int l = 0; l < 4; ++l) {
            const int idx = tid + (l << 8);
            const int ss = idx >> 4;
            const int dc = (idx & 15) << 2;
            const int s = (c << 6) + ss;
            float4 v4 = make_float4(0.f, 0.f, 0.f, 0.f);
            if (s < TT) v4 = *(const float4*)(k + (size_t)s * HD + dc);
            Stg[dc + 0][ss] = v4.x; Stg[dc + 1][ss] = v4.y;
            Stg[dc + 2][ss] = v4.z; Stg[dc + 3][ss] = v4.w;
        }
        __syncthreads();
        float acc[4][4] = {};
        #pragma unroll 4
        for (int d = 0; d < 64; ++d) {
            const float4 a4 = *(const float4*)&Stg[d][ty << 2];  // ss dir
            const float4 b4 = *(const float4*)&Qt[d][tx << 2];   // row dir
            const float aa[4] = {a4.x, a4.y, a4.z, a4.w};
            const float bb[4] = {b4.x, b4.y, b4.z, b4.w};
            #pragma unroll
            for (int i = 0; i < 4; ++i)
                #pragma unroll
                for (int n = 0; n < 4; ++n)
                    acc[i][n] = fmaf(aa[i], bb[n], acc[i][n]);
        }
        #pragma unroll
        for (int i = 0; i < 4; ++i) {
            const int s = (c << 6) + (ty << 2) + i;
            *(float4*)&ST[s][tx << 2] =
                make_float4(acc[i][0] * 0.125f, acc[i][1] * 0.125f,
                            acc[i][2] * 0.125f, acc[i][3] * 0.125f);
        }
    }
    __syncthreads();

    // -------- Phase 2: softmax + blend --------
    {
        const int prow = tid >> 2, part = tid & 3;
        if (prow < rows) {
            float mx = -1e30f;
            for (int s = part; s < TT; s += 4) mx = fmaxf(mx, ST[s][prow]);
            mx = fmaxf(mx, __shfl_xor(mx, 1));
            mx = fmaxf(mx, __shfl_xor(mx, 2));
            float l = 0.f;
            for (int s = part; s < TT; s += 4) l += __expf(ST[s][prow] - mx);
            l += __shfl_xor(l, 1);
            l += __shfl_xor(l, 2);
            const float sw = w / l;
            const float aw = 1.f - w;
            const float* amr = am + (size_t)(row0 + prow) * TT;
            for (int s = part; s < TT; s += 4)
                ST[s][prow] = __expf(ST[s][prow] - mx) * sw + aw * amr[s];
            for (int s = TT + part; s < 256; s += 4) ST[s][prow] = 0.f;
        } else {
            for (int s = part; s < 256; s += 4) ST[s][prow] = 0.f;
        }
    }
    __syncthreads();

    // -------- Phase 3: O = P @ V --------
    float oacc[4][4] = {};
    for (int c = 0; c < 4; ++c) {
        #pragma unroll
        for (int l = 0; l < 4; ++l) {
            const int idx = tid + (l << 8);
            const int sl = idx >> 4;
            const int dc = (idx & 15) << 2;
            const int s = (c << 6) + sl;
            float4 v4 = make_float4(0.f, 0.f, 0.f, 0.f);
            if (s < TT) v4 = *(const float4*)(v + (size_t)s * HD + dc);
            *(float4*)&Stg[sl][dc] = v4;                  // natural layout [sl][d]
        }
        __syncthreads();
        #pragma unroll 4
        for (int sl = 0; sl < 64; ++sl) {
            const float4 a4 = *(const float4*)&ST[(c << 6) + sl][ty << 2]; // rows
            const float4 b4 = *(const float4*)&Stg[sl][tx << 2];           // d
            const float aa[4] = {a4.x, a4.y, a4.z, a4.w};
            const float bb[4] = {b4.x, b4.y, b4.z, b4.w};
            #pragma unroll
            for (int i = 0; i < 4; ++i)
                #pragma unroll
                for (int n = 0; n < 4; ++n)
                    oacc[i][n] = fmaf(aa[i], bb[n], oacc[i][n]);
        }
        __syncthreads();
    }

    // store O rows into o buffer laid out [B,T,J,512], channel = h*64+d
    const int b  = bhj / HJ;
    const int hj = bhj - b * HJ;
    const int h  = hj / JJ;
    const int j  = hj - h * JJ;
    #pragma unroll
    for (int i = 0; i < 4; ++i) {
        const int r = (ty << 2) + i;
        if (r < rows) {
            const int t = row0 + r;
            float* orow = ob + ((size_t)((b * TT + t) * JJ + j) << 9) + (h << 6) + (tx << 2);
            *(float4*)orow = make_float4(oacc[i][0], oacc[i][1], oacc[i][2], oacc[i][3]);
        }
    }
}

// ---------------------------------------------------------------------------
// Kernel 3: out = o @ W_proj + b_proj   (rows already in [B,T,J,512] order)
// ---------------------------------------------------------------------------
__global__ __launch_bounds__(256) void proj_gemm(
    const float* __restrict__ o, const float* __restrict__ Wp,
    const float* __restrict__ bias, float* __restrict__ out)
{
    __shared__ float As[16][68];
    __shared__ float Bs[16][68];
    const int tid = threadIdx.x;
    const int tx = tid & 15, ty = tid >> 4;
    const int m0 = blockIdx.y * 64;
    const int n0 = blockIdx.x * 64;
    const int ar = tid >> 2, akc = (tid & 3) << 2;
    const int br = tid >> 4, bc = (tid & 15) << 2;
    float acc[4][4] = {};

    for (int k0 = 0; k0 < 512; k0 += 16) {
        float4 a4 = make_float4(0.f, 0.f, 0.f, 0.f);
        const int amr = m0 + ar;
        if (amr < MROWS) a4 = *(const float4*)(o + (size_t)amr * 512 + k0 + akc);
        const float4 b4 = *(const float4*)(Wp + (size_t)(k0 + br) * 512 + n0 + bc);
        __syncthreads();
        As[akc + 0][ar] = a4.x; As[akc + 1][ar] = a4.y;
        As[akc + 2][ar] = a4.z; As[akc + 3][ar] = a4.w;
        *(float4*)&Bs[br][bc] = b4;
        __syncthreads();
        #pragma unroll
        for (int k = 0; k < 16; ++k) {
            const float4 av = *(const float4*)&As[k][ty << 2];
            const float4 bv = *(const float4*)&Bs[k][tx << 2];
            const float aa[4] = {av.x, av.y, av.z, av.w};
            const float bb[4] = {bv.x, bv.y, bv.z, bv.w};
            #pragma unroll
            for (int i = 0; i < 4; ++i)
                #pragma unroll
                for (int n = 0; n < 4; ++n)
                    acc[i][n] = fmaf(aa[i], bb[n], acc[i][n]);
        }
    }

    const float4 bi = *(const float4*)(bias + n0 + (tx << 2));
    #pragma unroll
    for (int i = 0; i < 4; ++i) {
        const int m = m0 + (ty << 2) + i;
        if (m < MROWS) {
            *(float4*)(out + (size_t)m * 512 + n0 + (tx << 2)) =
                make_float4(acc[i][0] + bi.x, acc[i][1] + bi.y,
                            acc[i][2] + bi.z, acc[i][3] + bi.w);
        }
    }
}

// ---------------------------------------------------------------------------
extern "C" void kernel_launch(void* const* d_in, const int* in_sizes, int n_in,
                              void* d_out, int out_size, void* d_ws, size_t ws_size,
                              hipStream_t stream)
{
    const float* x    = (const float*)d_in[0];
    const float* att  = (const float*)d_in[1];
    const float* wgt  = (const float*)d_in[2];
    const float* Wqkv = (const float*)d_in[3];
    const float* Wp   = (const float*)d_in[4];
    const float* bp   = (const float*)d_in[5];
    float* out = (float*)d_out;

    const size_t SZ = (size_t)MROWS * 512;   // 16,920,576 floats per buffer
    float* qb = (float*)d_ws;
    float* kb = qb + SZ;
    float* vb = kb + SZ;
    float* ob = vb + SZ;                      // total ws use: 4*SZ*4B = 270.7 MB

    dim3 g1(24, 517);   // N=1536/64, M=ceil(33048/64)
    qkv_gemm<<<g1, 256, 0, stream>>>(x, Wqkv, qb, kb, vb);

    attn_fused<<<dim3(1088 * 4), 256, 0, stream>>>(qb, kb, vb, att, wgt, ob);

    dim3 g3(8, 517);    // N=512/64
    proj_gemm<<<g3, 256, 0, stream>>>(ob, Wp, bp, out);
}

// Round 2
// 885.597 us; speedup vs baseline: 2.0938x; 2.0938x over previous
//
#include <hip/hip_runtime.h>
#include <cstddef>
#include <cstdint>

#define NHEADS 8
#define TT 243
#define JJ 17
#define BB 8
#define CC 512
#define HD 64
#define MROWS 33048      // B*T*J
#define TJ 4131          // T*J
#define HJ 136           // H*J

typedef __attribute__((ext_vector_type(8))) short bf16x8;
typedef __attribute__((ext_vector_type(4))) float f32x4;

__device__ __forceinline__ unsigned short f2bf(float f) {
    unsigned u = __float_as_uint(f);
    unsigned r = (u + 0x7fff + ((u >> 16) & 1)) >> 16;   // RNE
    return (unsigned short)r;
}
__device__ __forceinline__ float b2f(unsigned short u) {
    return __uint_as_float(((unsigned)u) << 16);
}
__device__ __forceinline__ void async16(const void* g, void* l) {
    __builtin_amdgcn_global_load_lds(
        (const __attribute__((address_space(1))) void*)g,
        (__attribute__((address_space(3))) void*)l, 16, 0, 0);
}

// ---------------------------------------------------------------------------
// prep: x fp32 -> bf16 (same layout)
// ---------------------------------------------------------------------------
__global__ __launch_bounds__(256) void convert_x(
    const float* __restrict__ in, unsigned short* __restrict__ out, int n4)
{
    for (int i = blockIdx.x * 256 + threadIdx.x; i < n4; i += gridDim.x * 256) {
        const float4 v = *(const float4*)(in + (size_t)i * 4);
        ushort4 o;
        o.x = f2bf(v.x); o.y = f2bf(v.y); o.z = f2bf(v.z); o.w = f2bf(v.w);
        *(ushort4*)(out + (size_t)i * 4) = o;
    }
}

// ---------------------------------------------------------------------------
// prep: W fp32 [512][N] -> bf16 [N][512]  (transpose + convert)
// ---------------------------------------------------------------------------
__global__ __launch_bounds__(256) void transpose_w(
    const float* __restrict__ src, unsigned short* __restrict__ dst, int N)
{
    __shared__ unsigned short tile[64][65];
    const int tid = threadIdx.x;
    const int c = tid & 63, r4 = tid >> 6;
    const int n0 = blockIdx.x << 6, k0 = blockIdx.y << 6;
    #pragma unroll
    for (int p = 0; p < 16; ++p) {
        const int r = (p << 2) + r4;
        tile[r][c] = f2bf(src[(size_t)(k0 + r) * N + n0 + c]);
    }
    __syncthreads();
    #pragma unroll
    for (int p = 0; p < 16; ++p) {
        const int rr = (p << 2) + r4;
        dst[(size_t)(n0 + rr) * 512 + k0 + c] = tile[c][rr];
    }
}

// ---------------------------------------------------------------------------
// Kernel 1: bf16 MFMA GEMM  qkv = xb @ Wqkv  (Wqkvt pre-transposed [1536][512])
// 128x128 tile, BK=32, 4 waves, 16x16x32 mfma, scatter epilogue via LDS
// to q/k/v bf16 buffers laid out [B,H,J,T,hd].
// ---------------------------------------------------------------------------
__global__ __launch_bounds__(256) void gemm_qkv(
    const unsigned short* __restrict__ xb, const unsigned short* __restrict__ wt,
    unsigned short* __restrict__ qb, unsigned short* __restrict__ kb,
    unsigned short* __restrict__ vb)
{
    __shared__ unsigned short As[128 * 32];
    __shared__ unsigned short Bs[128 * 32];
    __shared__ unsigned short Cq[4][16][72];
    const int tid = threadIdx.x;
    const int wave = tid >> 6, lane = tid & 63;
    const int m0 = blockIdx.y << 7, n0 = blockIdx.x << 7;
    const int wr = wave >> 1, wc = wave & 1;

    f32x4 acc[4][4];
    #pragma unroll
    for (int i = 0; i < 4; ++i)
        #pragma unroll
        for (int j = 0; j < 4; ++j) acc[i][j] = (f32x4){0.f, 0.f, 0.f, 0.f};

    const int srow = lane >> 2;
    const int sbyte = (lane & 3) << 4;
    const int arow0 = (wave << 5) + srow;
    const int arow1 = arow0 + 16;
    const size_t am0 = (size_t)min(m0 + arow0, MROWS - 1);
    const size_t am1 = (size_t)min(m0 + arow1, MROWS - 1);
    const char* xbb = (const char*)xb;
    const char* wtb = (const char*)wt;
    char* Asb = (char*)As;
    char* Bsb = (char*)Bs;

    for (int k0 = 0; k0 < 512; k0 += 32) {
        __syncthreads();
        async16(xbb + (am0 * 512 + k0) * 2 + sbyte, Asb + ((wave << 5) << 6));
        async16(xbb + (am1 * 512 + k0) * 2 + sbyte, Asb + (((wave << 5) + 16) << 6));
        async16(wtb + ((size_t)(n0 + arow0) * 512 + k0) * 2 + sbyte, Bsb + ((wave << 5) << 6));
        async16(wtb + ((size_t)(n0 + arow1) * 512 + k0) * 2 + sbyte, Bsb + (((wave << 5) + 16) << 6));
        __syncthreads();
        bf16x8 af[4], bfr[4];
        #pragma unroll
        for (int i = 0; i < 4; ++i)
            af[i] = *(const bf16x8*)&As[((wr << 6) + (i << 4) + (lane & 15)) * 32 + ((lane >> 4) << 3)];
        #pragma unroll
        for (int j = 0; j < 4; ++j)
            bfr[j] = *(const bf16x8*)&Bs[((wc << 6) + (j << 4) + (lane & 15)) * 32 + ((lane >> 4) << 3)];
        #pragma unroll
        for (int i = 0; i < 4; ++i)
            #pragma unroll
            for (int j = 0; j < 4; ++j)
                acc[i][j] = __builtin_amdgcn_mfma_f32_16x16x32_bf16(af[i], bfr[j], acc[i][j], 0, 0, 0);
    }

    // epilogue: per 16-row chunk, transpose frags through LDS, vector-store
    const int nw = n0 + (wc << 6);
    const int which = nw >> 9;
    const int h = (nw >> 6) & 7;
    unsigned short* const dst = which == 0 ? qb : (which == 1 ? kb : vb);
    #pragma unroll
    for (int i = 0; i < 4; ++i) {
        #pragma unroll
        for (int j = 0; j < 4; ++j)
            #pragma unroll
            for (int r = 0; r < 4; ++r)
                Cq[wave][((lane >> 4) << 2) + r][(j << 4) + (lane & 15)] = f2bf(acc[i][j][r]);
        #pragma unroll
        for (int qq = 0; qq < 4; ++qq) {
            const int rr = (qq << 2) + (lane >> 4);
            const int ch = lane & 15;
            const ushort4 val = *(const ushort4*)&Cq[wave][rr][ch << 2];
            const int m = m0 + (wr << 6) + (i << 4) + rr;
            if (m < MROWS) {
                const int b = m / TJ; const int rm = m - b * TJ;
                const int t = rm / JJ; const int jj = rm - t * JJ;
                const size_t base = (((size_t)((b * NHEADS + h) * JJ + jj) * TT + t) << 6) + (ch << 2);
                *(ushort4*)(dst + base) = val;
            }
        }
    }
}

// ---------------------------------------------------------------------------
// Kernel 2: fused attention per (b,h,j, 64-row tile).  q/k/v bf16 in, bf16 out.
// ST stored bf16: LDS 69.6 KB -> 2 blocks/CU.
// ---------------------------------------------------------------------------
__global__ __launch_bounds__(256) void attn_fused(
    const unsigned short* __restrict__ qb, const unsigned short* __restrict__ kb,
    const unsigned short* __restrict__ vb, const float* __restrict__ att,
    const float* __restrict__ wptr, unsigned short* __restrict__ ob)
{
    __shared__ unsigned short ST[256][68];  // scores, then P (bf16)
    __shared__ float Qt[64][68];            // [d][row]
    __shared__ float Stg[64][68];           // K chunk [d][ss] / V chunk [sl][d]

    const int tid = threadIdx.x;
    const int tx = tid & 15, ty = tid >> 4;
    const int gid = blockIdx.x;
    const int tile = gid & 3, bhj = gid >> 2;
    const int row0 = tile << 6;
    const int rows = min(64, TT - row0);

    const float w = wptr[0];
    const unsigned short* q = qb + (size_t)bhj * TT * HD;
    const unsigned short* k = kb + (size_t)bhj * TT * HD;
    const unsigned short* v = vb + (size_t)bhj * TT * HD;
    const float* am = att + (size_t)bhj * TT * TT;

    #pragma unroll
    for (int l = 0; l < 4; ++l) {
        const int idx = tid + (l << 8);
        const int r = idx >> 4;
        const int dc = (idx & 15) << 2;
        ushort4 u = make_ushort4(0, 0, 0, 0);
        if (r < rows) u = *(const ushort4*)(q + (size_t)(row0 + r) * HD + dc);
        Qt[dc + 0][r] = b2f(u.x); Qt[dc + 1][r] = b2f(u.y);
        Qt[dc + 2][r] = b2f(u.z); Qt[dc + 3][r] = b2f(u.w);
    }

    // -------- Phase 1: scores --------
    for (int c = 0; c < 4; ++c) {
        __syncthreads();
        #pragma unroll
        for (int l = 0; l < 4; ++l) {
            const int idx = tid + (l << 8);
            const int ss = idx >> 4;
            const int dc = (idx & 15) << 2;
            const int s = (c << 6) + ss;
            ushort4 u = make_ushort4(0, 0, 0, 0);
            if (s < TT) u = *(const ushort4*)(k + (size_t)s * HD + dc);
            Stg[dc + 0][ss] = b2f(u.x); Stg[dc + 1][ss] = b2f(u.y);
            Stg[dc + 2][ss] = b2f(u.z); Stg[dc + 3][ss] = b2f(u.w);
        }
        __syncthreads();
        float acc[4][4] = {};
        #pragma unroll 4
        for (int d = 0; d < 64; ++d) {
            const float4 a4 = *(const float4*)&Stg[d][ty << 2];
            const float4 b4 = *(const float4*)&Qt[d][tx << 2];
            const float aa[4] = {a4.x, a4.y, a4.z, a4.w};
            const float bb[4] = {b4.x, b4.y, b4.z, b4.w};
            #pragma unroll
            for (int i = 0; i < 4; ++i)
                #pragma unroll
                for (int n = 0; n < 4; ++n)
                    acc[i][n] = fmaf(aa[i], bb[n], acc[i][n]);
        }
        #pragma unroll
        for (int i = 0; i < 4; ++i) {
            const int s = (c << 6) + (ty << 2) + i;
            ushort4 o;
            o.x = f2bf(acc[i][0] * 0.125f); o.y = f2bf(acc[i][1] * 0.125f);
            o.z = f2bf(acc[i][2] * 0.125f); o.w = f2bf(acc[i][3] * 0.125f);
            *(ushort4*)&ST[s][tx << 2] = o;
        }
    }
    __syncthreads();

    // -------- Phase 2: softmax + blend --------
    {
        const int prow = tid >> 2, part = tid & 3;
        if (prow < rows) {
            float mx = -1e30f;
            for (int s = part; s < TT; s += 4) mx = fmaxf(mx, b2f(ST[s][prow]));
            mx = fmaxf(mx, __shfl_xor(mx, 1));
            mx = fmaxf(mx, __shfl_xor(mx, 2));
            float l = 0.f;
            for (int s = part; s < TT; s += 4) l += __expf(b2f(ST[s][prow]) - mx);
            l += __shfl_xor(l, 1);
            l += __shfl_xor(l, 2);
            const float sw = w / l;
            const float aw = 1.f - w;
            const float* amr = am + (size_t)(row0 + prow) * TT;
            for (int s = part; s < TT; s += 4)
                ST[s][prow] = f2bf(__expf(b2f(ST[s][prow]) - mx) * sw + aw * amr[s]);
            for (int s = TT + part; s < 256; s += 4) ST[s][prow] = 0;
        } else {
            for (int s = part; s < 256; s += 4) ST[s][prow] = 0;
        }
    }
    __syncthreads();

    // -------- Phase 3: O = P @ V --------
    float oacc[4][4] = {};
    for (int c = 0; c < 4; ++c) {
        #pragma unroll
        for (int l = 0; l < 4; ++l) {
            const int idx = tid + (l << 8);
            const int sl = idx >> 4;
            const int dc = (idx & 15) << 2;
            const int s = (c << 6) + sl;
            ushort4 u = make_ushort4(0, 0, 0, 0);
            if (s < TT) u = *(const ushort4*)(v + (size_t)s * HD + dc);
            float4 f;
            f.x = b2f(u.x); f.y = b2f(u.y); f.z = b2f(u.z); f.w = b2f(u.w);
            *(float4*)&Stg[sl][dc] = f;
        }
        __syncthreads();
        #pragma unroll 4
        for (int sl = 0; sl < 64; ++sl) {
            const ushort4 au = *(const ushort4*)&ST[(c << 6) + sl][ty << 2];
            const float4 b4 = *(const float4*)&Stg[sl][tx << 2];
            const float aa[4] = {b2f(au.x), b2f(au.y), b2f(au.z), b2f(au.w)};
            const float bb[4] = {b4.x, b4.y, b4.z, b4.w};
            #pragma unroll
            for (int i = 0; i < 4; ++i)
                #pragma unroll
                for (int n = 0; n < 4; ++n)
                    oacc[i][n] = fmaf(aa[i], bb[n], oacc[i][n]);
        }
        __syncthreads();
    }

    const int b = bhj / HJ;
    const int hj = bhj - b * HJ;
    const int h = hj / JJ;
    const int j = hj - h * JJ;
    #pragma unroll
    for (int i = 0; i < 4; ++i) {
        const int r = (ty << 2) + i;
        if (r < rows) {
            const int t = row0 + r;
            unsigned short* orow = ob + ((size_t)((b * TT + t) * JJ + j) << 9) + (h << 6) + (tx << 2);
            ushort4 o;
            o.x = f2bf(oacc[i][0]); o.y = f2bf(oacc[i][1]);
            o.z = f2bf(oacc[i][2]); o.w = f2bf(oacc[i][3]);
            *(ushort4*)orow = o;
        }
    }
}

// ---------------------------------------------------------------------------
// Kernel 3: bf16 MFMA GEMM  out = ob @ Wp + bias  (Wpt pre-transposed [512][512])
// ---------------------------------------------------------------------------
__global__ __launch_bounds__(256) void gemm_proj(
    const unsigned short* __restrict__ obb, const unsigned short* __restrict__ wt,
    const float* __restrict__ bias, float* __restrict__ out)
{
    __shared__ unsigned short As[128 * 32];
    __shared__ unsigned short Bs[128 * 32];
    __shared__ float Cp[4][16][68];
    const int tid = threadIdx.x;
    const int wave = tid >> 6, lane = tid & 63;
    const int m0 = blockIdx.y << 7, n0 = blockIdx.x << 7;
    const int wr = wave >> 1, wc = wave & 1;

    f32x4 acc[4][4];
    #pragma unroll
    for (int i = 0; i < 4; ++i)
        #pragma unroll
        for (int j = 0; j < 4; ++j) acc[i][j] = (f32x4){0.f, 0.f, 0.f, 0.f};

    const int srow = lane >> 2;
    const int sbyte = (lane & 3) << 4;
    const int arow0 = (wave << 5) + srow;
    const int arow1 = arow0 + 16;
    const size_t am0 = (size_t)min(m0 + arow0, MROWS - 1);
    const size_t am1 = (size_t)min(m0 + arow1, MROWS - 1);
    const char* ab = (const char*)obb;
    const char* wtb = (const char*)wt;
    char* Asb = (char*)As;
    char* Bsb = (char*)Bs;

    for (int k0 = 0; k0 < 512; k0 += 32) {
        __syncthreads();
        async16(ab + (am0 * 512 + k0) * 2 + sbyte, Asb + ((wave << 5) << 6));
        async16(ab + (am1 * 512 + k0) * 2 + sbyte, Asb + (((wave << 5) + 16) << 6));
        async16(wtb + ((size_t)(n0 + arow0) * 512 + k0) * 2 + sbyte, Bsb + ((wave << 5) << 6));
        async16(wtb + ((size_t)(n0 + arow1) * 512 + k0) * 2 + sbyte, Bsb + (((wave << 5) + 16) << 6));
        __syncthreads();
        bf16x8 af[4], bfr[4];
        #pragma unroll
        for (int i = 0; i < 4; ++i)
            af[i] = *(const bf16x8*)&As[((wr << 6) + (i << 4) + (lane & 15)) * 32 + ((lane >> 4) << 3)];
        #pragma unroll
        for (int j = 0; j < 4; ++j)
            bfr[j] = *(const bf16x8*)&Bs[((wc << 6) + (j << 4) + (lane & 15)) * 32 + ((lane >> 4) << 3)];
        #pragma unroll
        for (int i = 0; i < 4; ++i)
            #pragma unroll
            for (int j = 0; j < 4; ++j)
                acc[i][j] = __builtin_amdgcn_mfma_f32_16x16x32_bf16(af[i], bfr[j], acc[i][j], 0, 0, 0);
    }

    const int ch0 = lane & 15;
    const float4 bvec = *(const float4*)&bias[n0 + (wc << 6) + (ch0 << 2)];
    #pragma unroll
    for (int i = 0; i < 4; ++i) {
        #pragma unroll
        for (int j = 0; j < 4; ++j)
            #pragma unroll
            for (int r = 0; r < 4; ++r)
                Cp[wave][((lane >> 4) << 2) + r][(j << 4) + (lane & 15)] = acc[i][j][r];
        #pragma unroll
        for (int qq = 0; qq < 4; ++qq) {
            const int rr = (qq << 2) + (lane >> 4);
            const int ch = lane & 15;
            float4 val = *(const float4*)&Cp[wave][rr][ch << 2];
            const int m = m0 + (wr << 6) + (i << 4) + rr;
            if (m < MROWS) {
                val.x += bvec.x; val.y += bvec.y; val.z += bvec.z; val.w += bvec.w;
                *(float4*)(out + (size_t)m * 512 + n0 + (wc << 6) + (ch << 2)) = val;
            }
        }
    }
}

// ---------------------------------------------------------------------------
extern "C" void kernel_launch(void* const* d_in, const int* in_sizes, int n_in,
                              void* d_out, int out_size, void* d_ws, size_t ws_size,
                              hipStream_t stream)
{
    const float* x    = (const float*)d_in[0];
    const float* att  = (const float*)d_in[1];
    const float* wgt  = (const float*)d_in[2];
    const float* Wqkv = (const float*)d_in[3];
    const float* Wp   = (const float*)d_in[4];
    const float* bp   = (const float*)d_in[5];
    float* out = (float*)d_out;

    const size_t SZ = (size_t)MROWS * 512;        // 16,920,576
    unsigned short* xb    = (unsigned short*)d_ws;
    unsigned short* wqkvt = xb + SZ;
    unsigned short* wpt   = wqkvt + (size_t)1536 * 512;
    unsigned short* qb    = wpt + (size_t)512 * 512;
    unsigned short* kb    = qb + SZ;
    unsigned short* vb    = kb + SZ;
    unsigned short* ob    = vb + SZ;              // total ~171.3 MB

    convert_x<<<4096, 256, 0, stream>>>(x, xb, (int)(SZ / 4));
    transpose_w<<<dim3(24, 8), 256, 0, stream>>>(Wqkv, wqkvt, 1536);
    transpose_w<<<dim3(8, 8), 256, 0, stream>>>(Wp, wpt, 512);

    gemm_qkv<<<dim3(12, 259), 256, 0, stream>>>(xb, wqkvt, qb, kb, vb);

    attn_fused<<<dim3(1088 * 4), 256, 0, stream>>>(qb, kb, vb, att, wgt, ob);

    gemm_proj<<<dim3(4, 259), 256, 0, stream>>>(ob, wpt, bp, out);
}

// Round 3
// 611.739 us; speedup vs baseline: 3.0311x; 1.4477x over previous
//
#include <hip/hip_runtime.h>
#include <cstddef>
#include <cstdint>

#define NHEADS 8
#define TT 243
#define JJ 17
#define BB 8
#define CC 512
#define HD 64
#define MROWS 33048      // B*T*J
#define TJ 4131          // T*J
#define HJ 136           // H*J

typedef __attribute__((ext_vector_type(8))) short bf16x8;
typedef __attribute__((ext_vector_type(4))) float f32x4;

__device__ __forceinline__ unsigned short f2bf(float f) {
    unsigned u = __float_as_uint(f);
    unsigned r = (u + 0x7fff + ((u >> 16) & 1)) >> 16;   // RNE
    return (unsigned short)r;
}
__device__ __forceinline__ float b2f(unsigned short u) {
    return __uint_as_float(((unsigned)u) << 16);
}
__device__ __forceinline__ void async16(const void* g, void* l) {
    __builtin_amdgcn_global_load_lds(
        (const __attribute__((address_space(1))) void*)g,
        (__attribute__((address_space(3))) void*)l, 16, 0, 0);
}

// ---------------------------------------------------------------------------
// prep: x fp32 -> bf16 (same layout)
// ---------------------------------------------------------------------------
__global__ __launch_bounds__(256) void convert_x(
    const float* __restrict__ in, unsigned short* __restrict__ out, int n4)
{
    for (int i = blockIdx.x * 256 + threadIdx.x; i < n4; i += gridDim.x * 256) {
        const float4 v = *(const float4*)(in + (size_t)i * 4);
        ushort4 o;
        o.x = f2bf(v.x); o.y = f2bf(v.y); o.z = f2bf(v.z); o.w = f2bf(v.w);
        *(ushort4*)(out + (size_t)i * 4) = o;
    }
}

// ---------------------------------------------------------------------------
// prep: W fp32 [512][N] -> bf16 [N][512]  (transpose + convert)
// ---------------------------------------------------------------------------
__global__ __launch_bounds__(256) void transpose_w(
    const float* __restrict__ src, unsigned short* __restrict__ dst, int N)
{
    __shared__ unsigned short tile[64][65];
    const int tid = threadIdx.x;
    const int c = tid & 63, r4 = tid >> 6;
    const int n0 = blockIdx.x << 6, k0 = blockIdx.y << 6;
    #pragma unroll
    for (int p = 0; p < 16; ++p) {
        const int r = (p << 2) + r4;
        tile[r][c] = f2bf(src[(size_t)(k0 + r) * N + n0 + c]);
    }
    __syncthreads();
    #pragma unroll
    for (int p = 0; p < 16; ++p) {
        const int rr = (p << 2) + r4;
        dst[(size_t)(n0 + rr) * 512 + k0 + c] = tile[c][rr];
    }
}

// ---------------------------------------------------------------------------
// Kernel 1: bf16 MFMA GEMM  qkv = xb @ Wqkv  (Wqkvt pre-transposed [1536][512])
// ---------------------------------------------------------------------------
__global__ __launch_bounds__(256) void gemm_qkv(
    const unsigned short* __restrict__ xb, const unsigned short* __restrict__ wt,
    unsigned short* __restrict__ qb, unsigned short* __restrict__ kb,
    unsigned short* __restrict__ vb)
{
    __shared__ unsigned short As[128 * 32];
    __shared__ unsigned short Bs[128 * 32];
    __shared__ unsigned short Cq[4][16][72];
    const int tid = threadIdx.x;
    const int wave = tid >> 6, lane = tid & 63;
    const int m0 = blockIdx.y << 7, n0 = blockIdx.x << 7;
    const int wr = wave >> 1, wc = wave & 1;

    f32x4 acc[4][4];
    #pragma unroll
    for (int i = 0; i < 4; ++i)
        #pragma unroll
        for (int j = 0; j < 4; ++j) acc[i][j] = (f32x4){0.f, 0.f, 0.f, 0.f};

    const int srow = lane >> 2;
    const int sbyte = (lane & 3) << 4;
    const int arow0 = (wave << 5) + srow;
    const int arow1 = arow0 + 16;
    const size_t am0 = (size_t)min(m0 + arow0, MROWS - 1);
    const size_t am1 = (size_t)min(m0 + arow1, MROWS - 1);
    const char* xbb = (const char*)xb;
    const char* wtb = (const char*)wt;
    char* Asb = (char*)As;
    char* Bsb = (char*)Bs;

    for (int k0 = 0; k0 < 512; k0 += 32) {
        __syncthreads();
        async16(xbb + (am0 * 512 + k0) * 2 + sbyte, Asb + ((wave << 5) << 6));
        async16(xbb + (am1 * 512 + k0) * 2 + sbyte, Asb + (((wave << 5) + 16) << 6));
        async16(wtb + ((size_t)(n0 + arow0) * 512 + k0) * 2 + sbyte, Bsb + ((wave << 5) << 6));
        async16(wtb + ((size_t)(n0 + arow1) * 512 + k0) * 2 + sbyte, Bsb + (((wave << 5) + 16) << 6));
        __syncthreads();
        bf16x8 af[4], bfr[4];
        #pragma unroll
        for (int i = 0; i < 4; ++i)
            af[i] = *(const bf16x8*)&As[((wr << 6) + (i << 4) + (lane & 15)) * 32 + ((lane >> 4) << 3)];
        #pragma unroll
        for (int j = 0; j < 4; ++j)
            bfr[j] = *(const bf16x8*)&Bs[((wc << 6) + (j << 4) + (lane & 15)) * 32 + ((lane >> 4) << 3)];
        #pragma unroll
        for (int i = 0; i < 4; ++i)
            #pragma unroll
            for (int j = 0; j < 4; ++j)
                acc[i][j] = __builtin_amdgcn_mfma_f32_16x16x32_bf16(af[i], bfr[j], acc[i][j], 0, 0, 0);
    }

    const int nw = n0 + (wc << 6);
    const int which = nw >> 9;
    const int h = (nw >> 6) & 7;
    unsigned short* const dst = which == 0 ? qb : (which == 1 ? kb : vb);
    #pragma unroll
    for (int i = 0; i < 4; ++i) {
        #pragma unroll
        for (int j = 0; j < 4; ++j)
            #pragma unroll
            for (int r = 0; r < 4; ++r)
                Cq[wave][((lane >> 4) << 2) + r][(j << 4) + (lane & 15)] = f2bf(acc[i][j][r]);
        #pragma unroll
        for (int qq = 0; qq < 4; ++qq) {
            const int rr = (qq << 2) + (lane >> 4);
            const int ch = lane & 15;
            const ushort4 val = *(const ushort4*)&Cq[wave][rr][ch << 2];
            const int m = m0 + (wr << 6) + (i << 4) + rr;
            if (m < MROWS) {
                const int b = m / TJ; const int rm = m - b * TJ;
                const int t = rm / JJ; const int jj = rm - t * JJ;
                const size_t base = (((size_t)((b * NHEADS + h) * JJ + jj) * TT + t) << 6) + (ch << 2);
                *(ushort4*)(dst + base) = val;
            }
        }
    }
}

// ---------------------------------------------------------------------------
// vtrans: vb [bhj][t][64] -> vt [bhj][64][256] (d-major, zero-padded t,
// 8-short chunks XOR-swizzled by d&7 for conflict-free LDS B-frag reads)
// ---------------------------------------------------------------------------
__global__ __launch_bounds__(256) void vtrans(
    const unsigned short* __restrict__ vb, unsigned short* __restrict__ vt)
{
    __shared__ unsigned short TL[64 * 264];
    const int tid = threadIdx.x;
    const int bhj = blockIdx.x;
    const unsigned short* src = vb + (size_t)bhj * TT * HD;

    {   // zero cols 240..255 (covers the t>=243 padding; 240..242 rewritten)
        const int d = tid >> 2, qq = tid & 3;
        *(ushort4*)(TL + d * 264 + 240 + (qq << 2)) = make_ushort4(0, 0, 0, 0);
    }
    __syncthreads();
    #pragma unroll
    for (int p = 0; p < 16; ++p) {
        const int idxq = tid + (p << 8);
        const int t = idxq >> 4;
        if (t < TT) {
            const int d0 = (idxq & 15) << 2;
            const ushort4 u = *(const ushort4*)(src + t * HD + d0);
            TL[(d0 + 0) * 264 + t] = u.x;
            TL[(d0 + 1) * 264 + t] = u.y;
            TL[(d0 + 2) * 264 + t] = u.z;
            TL[(d0 + 3) * 264 + t] = u.w;
        }
    }
    __syncthreads();
    unsigned short* dst = vt + ((size_t)bhj << 14);
    #pragma unroll
    for (int p = 0; p < 8; ++p) {
        const int cw = tid + (p << 8);           // 2048 chunk-writes
        const int d = cw >> 5, c = cw & 31;
        const ushort4 a = *(const ushort4*)(TL + d * 264 + (c << 3));
        const ushort4 bq = *(const ushort4*)(TL + d * 264 + (c << 3) + 4);
        const int oc = (c ^ (d & 7)) << 3;
        *(ushort4*)(dst + (d << 8) + oc) = a;
        *(ushort4*)(dst + (d << 8) + oc + 4) = bq;
    }
}

// ---------------------------------------------------------------------------
// Kernel 2: MFMA attention. block = (bhj, 64-row tile), 4 waves.
// Phase1: wave w computes S[:, 64w..64w+64) = Q K^T via 16x16x32 mfma,
//         Q/K frags straight from global (K-major rows = frag layout).
// Phase2: row-parallel softmax + blend over row-major bf16 S in LDS.
// Phase3: O = P @ Vt, Vt staged in LDS via async16 (XOR-swizzled chunks).
// ---------------------------------------------------------------------------
__global__ __launch_bounds__(256) void attn_mfma(
    const unsigned short* __restrict__ qb, const unsigned short* __restrict__ kb,
    const unsigned short* __restrict__ vt, const float* __restrict__ att,
    const float* __restrict__ wptr, unsigned short* __restrict__ ob)
{
    __shared__ unsigned short ST[64 * 264];   // S / P, row-major bf16
    __shared__ unsigned short VT[64 * 256];   // V^T, swizzled

    const int tid = threadIdx.x;
    const int wave = tid >> 6, lane = tid & 63;
    const int tile = blockIdx.x & 3, bhj = blockIdx.x >> 2;
    const int row0 = tile << 6;

    const unsigned short* q = qb + (size_t)bhj * TT * HD;
    const unsigned short* k = kb + (size_t)bhj * TT * HD;
    const float* am = att + (size_t)bhj * TT * TT;
    const float w = wptr[0];

    // stage Vt into LDS (exact global image, incl. swizzle + zero pad)
    {
        const char* vtb = (const char*)(vt + ((size_t)bhj << 14));
        char* VTb = (char*)VT;
        #pragma unroll
        for (int i = 0; i < 8; ++i) {
            const int off = ((wave << 3) + i) << 10;
            async16(vtb + off + (lane << 4), VTb + off);
        }
    }

    // ---- Phase 1 ----
    const int lm = lane & 15, lk = lane >> 4;
    bf16x8 qf[4][2];
    #pragma unroll
    for (int mi = 0; mi < 4; ++mi) {
        const int r = min(row0 + (mi << 4) + lm, TT - 1);
        #pragma unroll
        for (int kb2 = 0; kb2 < 2; ++kb2)
            qf[mi][kb2] = *(const bf16x8*)(q + r * HD + (kb2 << 5) + (lk << 3));
    }
    f32x4 acc[4][4];
    #pragma unroll
    for (int mi = 0; mi < 4; ++mi)
        #pragma unroll
        for (int nj = 0; nj < 4; ++nj) acc[mi][nj] = (f32x4){0.f, 0.f, 0.f, 0.f};
    #pragma unroll
    for (int kb2 = 0; kb2 < 2; ++kb2) {
        bf16x8 kf[4];
        #pragma unroll
        for (int nj = 0; nj < 4; ++nj) {
            const int s = min((wave << 6) + (nj << 4) + lm, TT - 1);
            kf[nj] = *(const bf16x8*)(k + s * HD + (kb2 << 5) + (lk << 3));
        }
        #pragma unroll
        for (int mi = 0; mi < 4; ++mi)
            #pragma unroll
            for (int nj = 0; nj < 4; ++nj)
                acc[mi][nj] = __builtin_amdgcn_mfma_f32_16x16x32_bf16(qf[mi][kb2], kf[nj], acc[mi][nj], 0, 0, 0);
    }
    #pragma unroll
    for (int mi = 0; mi < 4; ++mi)
        #pragma unroll
        for (int nj = 0; nj < 4; ++nj)
            #pragma unroll
            for (int r = 0; r < 4; ++r) {
                const int m = (mi << 4) + (lk << 2) + r;
                const int s = (wave << 6) + (nj << 4) + lm;
                ST[m * 264 + s] = f2bf(acc[mi][nj][r] * 0.125f);
            }
    __syncthreads();

    // ---- Phase 2: softmax + blend (4 threads per row) ----
    {
        const int row = tid >> 2, part = tid & 3;
        const int trow = row0 + row;
        unsigned short* strow = ST + row * 264;
        if (trow < TT) {
            float mx = -1e30f;
            #pragma unroll
            for (int i = 0; i < 15; ++i) {
                const ushort4 u = *(const ushort4*)(strow + (part << 2) + (i << 4));
                mx = fmaxf(fmaxf(fmaxf(fmaxf(mx, b2f(u.x)), b2f(u.y)), b2f(u.z)), b2f(u.w));
            }
            if (part == 0)
                for (int s = 240; s < TT; ++s) mx = fmaxf(mx, b2f(strow[s]));
            mx = fmaxf(mx, __shfl_xor(mx, 1));
            mx = fmaxf(mx, __shfl_xor(mx, 2));
            float l = 0.f;
            #pragma unroll
            for (int i = 0; i < 15; ++i) {
                const int s0 = (part << 2) + (i << 4);
                const ushort4 u = *(const ushort4*)(strow + s0);
                const float e0 = __expf(b2f(u.x) - mx), e1 = __expf(b2f(u.y) - mx);
                const float e2 = __expf(b2f(u.z) - mx), e3 = __expf(b2f(u.w) - mx);
                l += (e0 + e1) + (e2 + e3);
                ushort4 o;
                o.x = f2bf(e0); o.y = f2bf(e1); o.z = f2bf(e2); o.w = f2bf(e3);
                *(ushort4*)(strow + s0) = o;
            }
            if (part == 0)
                for (int s = 240; s < TT; ++s) {
                    const float e = __expf(b2f(strow[s]) - mx);
                    l += e; strow[s] = f2bf(e);
                }
            l += __shfl_xor(l, 1);
            l += __shfl_xor(l, 2);
            const float sw = w / l, aw = 1.f - w;
            const float* amr = am + (size_t)trow * TT;
            #pragma unroll
            for (int i = 0; i < 15; ++i) {
                const int s0 = (part << 2) + (i << 4);
                const ushort4 u = *(const ushort4*)(strow + s0);
                const float a0 = amr[s0], a1 = amr[s0 + 1], a2 = amr[s0 + 2], a3 = amr[s0 + 3];
                ushort4 o;
                o.x = f2bf(b2f(u.x) * sw + aw * a0);
                o.y = f2bf(b2f(u.y) * sw + aw * a1);
                o.z = f2bf(b2f(u.z) * sw + aw * a2);
                o.w = f2bf(b2f(u.w) * sw + aw * a3);
                *(ushort4*)(strow + s0) = o;
            }
            if (part == 0) {
                for (int s = 240; s < TT; ++s)
                    strow[s] = f2bf(b2f(strow[s]) * sw + aw * amr[s]);
                for (int s = TT; s < 256; ++s) strow[s] = 0;
            }
        } else {
            #pragma unroll
            for (int i = 0; i < 16; ++i)
                *(ushort4*)(strow + (part << 2) + (i << 4)) = make_ushort4(0, 0, 0, 0);
        }
    }
    __syncthreads();

    // ---- Phase 3: O = P @ Vt (wave w -> rows 16w..16w+15) ----
    f32x4 oacc[4];
    #pragma unroll
    for (int nj = 0; nj < 4; ++nj) oacc[nj] = (f32x4){0.f, 0.f, 0.f, 0.f};
    const unsigned short* strow3 = ST + ((wave << 4) + lm) * 264;
    #pragma unroll
    for (int kb8 = 0; kb8 < 8; ++kb8) {
        const bf16x8 pf = *(const bf16x8*)(strow3 + (kb8 << 5) + (lk << 3));
        #pragma unroll
        for (int nj = 0; nj < 4; ++nj) {
            const int d = (nj << 4) + lm;
            const int chunk = (kb8 << 2) + lk;
            const bf16x8 vf = *(const bf16x8*)(VT + (d << 8) + ((chunk ^ (d & 7)) << 3));
            oacc[nj] = __builtin_amdgcn_mfma_f32_16x16x32_bf16(pf, vf, oacc[nj], 0, 0, 0);
        }
    }

    const int b = bhj / HJ;
    const int hj = bhj - b * HJ;
    const int h = hj / JJ;
    const int j = hj - h * JJ;
    #pragma unroll
    for (int r = 0; r < 4; ++r) {
        const int t = row0 + (wave << 4) + (lk << 2) + r;
        if (t < TT) {
            unsigned short* orow = ob + (((size_t)((b * TT + t) * JJ + j)) << 9) + (h << 6);
            #pragma unroll
            for (int nj = 0; nj < 4; ++nj)
                orow[(nj << 4) + lm] = f2bf(oacc[nj][r]);
        }
    }
}

// ---------------------------------------------------------------------------
// Kernel 3: bf16 MFMA GEMM  out = ob @ Wp + bias  (Wpt pre-transposed)
// ---------------------------------------------------------------------------
__global__ __launch_bounds__(256) void gemm_proj(
    const unsigned short* __restrict__ obb, const unsigned short* __restrict__ wt,
    const float* __restrict__ bias, float* __restrict__ out)
{
    __shared__ unsigned short As[128 * 32];
    __shared__ unsigned short Bs[128 * 32];
    __shared__ float Cp[4][16][68];
    const int tid = threadIdx.x;
    const int wave = tid >> 6, lane = tid & 63;
    const int m0 = blockIdx.y << 7, n0 = blockIdx.x << 7;
    const int wr = wave >> 1, wc = wave & 1;

    f32x4 acc[4][4];
    #pragma unroll
    for (int i = 0; i < 4; ++i)
        #pragma unroll
        for (int j = 0; j < 4; ++j) acc[i][j] = (f32x4){0.f, 0.f, 0.f, 0.f};

    const int srow = lane >> 2;
    const int sbyte = (lane & 3) << 4;
    const int arow0 = (wave << 5) + srow;
    const int arow1 = arow0 + 16;
    const size_t am0 = (size_t)min(m0 + arow0, MROWS - 1);
    const size_t am1 = (size_t)min(m0 + arow1, MROWS - 1);
    const char* ab = (const char*)obb;
    const char* wtb = (const char*)wt;
    char* Asb = (char*)As;
    char* Bsb = (char*)Bs;

    for (int k0 = 0; k0 < 512; k0 += 32) {
        __syncthreads();
        async16(ab + (am0 * 512 + k0) * 2 + sbyte, Asb + ((wave << 5) << 6));
        async16(ab + (am1 * 512 + k0) * 2 + sbyte, Asb + (((wave << 5) + 16) << 6));
        async16(wtb + ((size_t)(n0 + arow0) * 512 + k0) * 2 + sbyte, Bsb + ((wave << 5) << 6));
        async16(wtb + ((size_t)(n0 + arow1) * 512 + k0) * 2 + sbyte, Bsb + (((wave << 5) + 16) << 6));
        __syncthreads();
        bf16x8 af[4], bfr[4];
        #pragma unroll
        for (int i = 0; i < 4; ++i)
            af[i] = *(const bf16x8*)&As[((wr << 6) + (i << 4) + (lane & 15)) * 32 + ((lane >> 4) << 3)];
        #pragma unroll
        for (int j = 0; j < 4; ++j)
            bfr[j] = *(const bf16x8*)&Bs[((wc << 6) + (j << 4) + (lane & 15)) * 32 + ((lane >> 4) << 3)];
        #pragma unroll
        for (int i = 0; i < 4; ++i)
            #pragma unroll
            for (int j = 0; j < 4; ++j)
                acc[i][j] = __builtin_amdgcn_mfma_f32_16x16x32_bf16(af[i], bfr[j], acc[i][j], 0, 0, 0);
    }

    const int ch0 = lane & 15;
    const float4 bvec = *(const float4*)&bias[n0 + (wc << 6) + (ch0 << 2)];
    #pragma unroll
    for (int i = 0; i < 4; ++i) {
        #pragma unroll
        for (int j = 0; j < 4; ++j)
            #pragma unroll
            for (int r = 0; r < 4; ++r)
                Cp[wave][((lane >> 4) << 2) + r][(j << 4) + (lane & 15)] = acc[i][j][r];
        #pragma unroll
        for (int qq = 0; qq < 4; ++qq) {
            const int rr = (qq << 2) + (lane >> 4);
            const int ch = lane & 15;
            float4 val = *(const float4*)&Cp[wave][rr][ch << 2];
            const int m = m0 + (wr << 6) + (i << 4) + rr;
            if (m < MROWS) {
                val.x += bvec.x; val.y += bvec.y; val.z += bvec.z; val.w += bvec.w;
                *(float4*)(out + (size_t)m * 512 + n0 + (wc << 6) + (ch << 2)) = val;
            }
        }
    }
}

// ---------------------------------------------------------------------------
extern "C" void kernel_launch(void* const* d_in, const int* in_sizes, int n_in,
                              void* d_out, int out_size, void* d_ws, size_t ws_size,
                              hipStream_t stream)
{
    const float* x    = (const float*)d_in[0];
    const float* att  = (const float*)d_in[1];
    const float* wgt  = (const float*)d_in[2];
    const float* Wqkv = (const float*)d_in[3];
    const float* Wp   = (const float*)d_in[4];
    const float* bp   = (const float*)d_in[5];
    float* out = (float*)d_out;

    const size_t SZ = (size_t)MROWS * 512;        // 16,920,576
    unsigned short* xb    = (unsigned short*)d_ws;
    unsigned short* wqkvt = xb + SZ;
    unsigned short* wpt   = wqkvt + (size_t)1536 * 512;
    unsigned short* qb    = wpt + (size_t)512 * 512;
    unsigned short* kb    = qb + SZ;
    unsigned short* vb    = kb + SZ;
    unsigned short* ob    = vb + SZ;
    unsigned short* vtb   = ob + SZ;              // 1088*64*256 shorts (~35.7 MB)

    convert_x<<<4096, 256, 0, stream>>>(x, xb, (int)(SZ / 4));
    transpose_w<<<dim3(24, 8), 256, 0, stream>>>(Wqkv, wqkvt, 1536);
    transpose_w<<<dim3(8, 8), 256, 0, stream>>>(Wp, wpt, 512);

    gemm_qkv<<<dim3(12, 259), 256, 0, stream>>>(xb, wqkvt, qb, kb, vb);

    vtrans<<<dim3(1088), 256, 0, stream>>>(vb, vtb);

    attn_mfma<<<dim3(1088 * 4), 256, 0, stream>>>(qb, kb, vtb, att, wgt, ob);

    gemm_proj<<<dim3(4, 259), 256, 0, stream>>>(ob, wpt, bp, out);
}